// Round 8
// baseline (461.424 us; speedup 1.0000x reference)
//
#include <hip/hip_runtime.h>
#include <math.h>

#define N_NODES 661
#define N_GRAPH 128
#define DEG 8
#define EPG (N_NODES*DEG)          // 5288 edges per graph per matrix
#define NTOT (N_NODES*N_GRAPH)     // 84608 nodes
#define FDIM 64
#define NF ((size_t)NTOT*FDIM)     // elements per [n,64] array
#define OSTR 672                   // padded CSR offsets stride
#define NTILE 22
#define TROWS 31                   // 22*31 = 682 >= 661

using short8  = __attribute__((ext_vector_type(8))) short;
using float4v = __attribute__((ext_vector_type(4))) float;

__device__ __forceinline__ unsigned short f2bf(float x) {
    unsigned int u = __float_as_uint(x);
    unsigned int r = u + 0x7FFFu + ((u >> 16) & 1u);
    return (unsigned short)(r >> 16);
}
__device__ __forceinline__ float bf2f(unsigned short h) {
    return __uint_as_float(((unsigned int)h) << 16);
}
__device__ __forceinline__ unsigned pack_bf(float x) {
    unsigned short h = f2bf(x);
    unsigned short l = f2bf(x - bf2f(h));
    return ((unsigned)h << 16) | (unsigned)l;
}

// ---------------------------------------------------------------------------
// Kernel 1 (fused): blocks 0..511 -> per-(graph,matrix) LDS counting sort ->
// CSR; blocks 512..591 -> wtrans (bf16 hi/lo W fragments in MFMA B-layout).
// ---------------------------------------------------------------------------
__global__ __launch_bounds__(256) void csr_build(
    const int* __restrict__ rG, const int* __restrict__ cG, const float* __restrict__ vG,
    const int* __restrict__ rB, const int* __restrict__ cB, const float* __restrict__ vB,
    const int* __restrict__ r1, const int* __restrict__ c1, const float* __restrict__ v1,
    const int* __restrict__ r2, const int* __restrict__ c2, const float* __restrict__ v2,
    const float* __restrict__ W1, const float* __restrict__ W2,
    unsigned short* __restrict__ Wb1h, unsigned short* __restrict__ Wb1l,
    unsigned short* __restrict__ Wb2h, unsigned short* __restrict__ Wb2l,
    int* __restrict__ offs_out, int2* __restrict__ pairs_out)
{
    int bid = blockIdx.x;
    int tid = threadIdx.x;

    if (bid >= 512) {                     // ---- wtrans part ----
        int i = (bid - 512)*256 + tid;    // 0..20479
        int j    = i & 7;
        int lane = (i >> 3) & 63;
        int ot   = (i >> 9) & 3;
        int ks   = i >> 11;
        int k = ks*32 + (lane >> 4)*8 + j;
        int o = ot*16 + (lane & 15);
        float w1 = W1[o*320 + k];
        float w2 = W2[o*320 + k];
        unsigned short h1 = f2bf(w1); Wb1h[i] = h1; Wb1l[i] = f2bf(w1 - bf2f(h1));
        unsigned short h2 = f2bf(w2); Wb2h[i] = h2; Wb2l[i] = f2bf(w2 - bf2f(h2));
        return;
    }

    __shared__ int   scount[N_NODES];
    __shared__ int   soffs[N_NODES+1];
    __shared__ int   scursor[N_NODES];
    __shared__ int   scol[EPG];
    __shared__ float sval[EPG];
    __shared__ int   sscan[256];

    int g = bid & 127;
    int m = bid >> 7;
    const int*   rows = (m==0)?rG:(m==1)?rB:(m==2)?r1:r2;
    const int*   cols = (m==0)?cG:(m==1)?cB:(m==2)?c1:c2;
    const float* vals = (m==0)?vG:(m==1)?vB:(m==2)?v1:v2;

    int ebase = g*EPG;
    int gbase = g*N_NODES;
    int seg = m*N_GRAPH + g;

    for (int i = tid; i < N_NODES; i += 256) scount[i] = 0;
    __syncthreads();
    for (int i = tid; i < EPG; i += 256)
        atomicAdd(&scount[rows[ebase+i] - gbase], 1);
    __syncthreads();

    int c0 = tid*3;
    int ps = 0;
    #pragma unroll
    for (int j = 0; j < 3; ++j) { int i = c0+j; if (i < N_NODES) ps += scount[i]; }
    sscan[tid] = ps;
    __syncthreads();
    #pragma unroll
    for (int d = 1; d < 256; d <<= 1) {
        int v = (tid >= d) ? sscan[tid-d] : 0;
        __syncthreads();
        sscan[tid] += v;
        __syncthreads();
    }
    int run = sscan[tid] - ps;   // exclusive prefix
    #pragma unroll
    for (int j = 0; j < 3; ++j) {
        int i = c0+j;
        if (i < N_NODES) { soffs[i] = run; scursor[i] = run; run += scount[i]; }
    }
    if (tid == 0) soffs[N_NODES] = EPG;
    __syncthreads();

    for (int i = tid; i < EPG; i += 256) {
        int r = rows[ebase+i] - gbase;
        int pos = atomicAdd(&scursor[r], 1);
        scol[pos] = cols[ebase+i];
        sval[pos] = vals[ebase+i];
    }
    __syncthreads();

    for (int i = tid; i <= N_NODES; i += 256)
        offs_out[(size_t)seg*OSTR + i] = soffs[i];
    int2* po = pairs_out + (size_t)seg*EPG;
    for (int i = tid; i < EPG; i += 256)
        po[i] = make_int2(scol[i], __float_as_int(sval[i]));
}

// ---------------------------------------------------------------------------
__device__ __forceinline__ void node_math1(
    float ev, float fv, float gd, float bd, float pd, float qd,
    float eGv, float fGv, float eBv, float fBv,
    float& e3v, float& nev, float& f3v, float& nfv)
{
    float invb = 1.0f/(ev*ev + fv*fv + 0.1f);
    float alpha = (pd*ev + qd*fv)*invb - eGv - fBv;
    float beta  = (qd*ev - pd*fv)*invb + fGv + eBv;
    float invg = 1.0f/(gd*gd + bd*bd);
    e3v = (alpha*gd + beta*bd)*invg;
    f3v = (beta*gd - alpha*bd)*invg;
    float bb1 = eGv - fBv, bb2 = fGv + eBv;
    float vv = ev*ev + fv*fv;
    float P_ = pd - vv*gd, Q_ = qd + vv*bd;
    nev = (P_*bb1 + Q_*bb2)*invg;
    nfv = (P_*bb2 - Q_*bb1)*invg;
}

// ---------------------------------------------------------------------------
// Kernel 2: gather SpMM v5. lane = feature; 2 rows per wave iteration, A/B
// batches of both rows interleaved -> 32 independent gathers in flight.
// Pair indices wave-uniform (scalarized). arrs packed bf16 hi|lo.
// Grid: 5632 = 8 XCD * 16 graphs * 44 (22 tiles x 2 sets).
// ---------------------------------------------------------------------------
__global__ __launch_bounds__(256) void gather_all(
    const float* __restrict__ e, const float* __restrict__ f,
    const float* __restrict__ Gd, const float* __restrict__ Bd,
    const float* __restrict__ Pd, const float* __restrict__ Qd,
    const float* __restrict__ w_ae, const float* __restrict__ w_af,
    const int* __restrict__ offs, const int2* __restrict__ pairs,
    unsigned* __restrict__ arrs, float* __restrict__ partials)
{
    int tid = threadIdx.x, lane = tid & 63, wv = tid >> 6;
    int bid = blockIdx.x;
    int xcd = bid & 7, loc = bid >> 3;          // loc 0..703
    int g    = xcd*16 + loc/44;
    int sub  = loc % 44;
    int set  = (sub < NTILE) ? 0 : 1;
    int tile = sub - set*NTILE;
    int r0   = tile*TROWS;
    int rlim = min(TROWS, N_NODES - r0);
    int mA = set ? 2 : 0, mB = set ? 3 : 1;

    const int*  poA = offs + (size_t)(mA*N_GRAPH + g)*OSTR;
    const int*  poB = offs + (size_t)(mB*N_GRAPH + g)*OSTR;
    const int2* ppA = pairs + (size_t)(mA*N_GRAPH + g)*EPG;
    const int2* ppB = pairs + (size_t)(mB*N_GRAPH + g)*EPG;

    float wa = w_ae[lane], wf = w_af[lane];
    float pa0 = 0.f, pa1 = 0.f, pa2 = 0.f, pa3 = 0.f;

    for (int lr = wv; lr < rlim; lr += 8) {
        int r1 = r0 + lr;
        int has2 = (lr + 4) < rlim;
        int r2 = has2 ? (r1 + 4) : r1;
        int node1 = g*N_NODES + r1;
        int node2 = g*N_NODES + r2;

        int s1A = __builtin_amdgcn_readfirstlane(poA[r1]);
        int t1A = __builtin_amdgcn_readfirstlane(poA[r1+1]);
        int s1B = __builtin_amdgcn_readfirstlane(poB[r1]);
        int t1B = __builtin_amdgcn_readfirstlane(poB[r1+1]);
        int s2A = __builtin_amdgcn_readfirstlane(poA[r2]);
        int t2A = __builtin_amdgcn_readfirstlane(poA[r2+1]);
        int s2B = __builtin_amdgcn_readfirstlane(poB[r2]);
        int t2B = __builtin_amdgcn_readfirstlane(poB[r2+1]);
        int d1A = t1A - s1A, d1B = t1B - s1B;
        int d2A = has2 ? (t2A - s2A) : 0;
        int d2B = has2 ? (t2B - s2B) : 0;
        int nmax = max(max(d1A, d1B), max(d2A, d2B));

        // prefetch epilogue inputs (independent of gather chain)
        size_t idx1 = (size_t)node1*FDIM + lane;
        size_t idx2 = (size_t)node2*FDIM + lane;
        float ev1 = 0.f, fv1 = 0.f, ev2 = 0.f, fv2 = 0.f;
        float gd1 = 0.f, bd1 = 0.f, pd1 = 0.f, qd1 = 0.f;
        float gd2 = 0.f, bd2 = 0.f, pd2 = 0.f, qd2 = 0.f;
        if (set == 0) {
            ev1 = e[idx1]; fv1 = f[idx1];
            gd1 = Gd[node1]; bd1 = Bd[node1]; pd1 = Pd[node1]; qd1 = Qd[node1];
            ev2 = e[idx2]; fv2 = f[idx2];
            gd2 = Gd[node2]; bd2 = Bd[node2]; pd2 = Pd[node2]; qd2 = Qd[node2];
        }

        float aE1=0.f, aF1=0.f, bE1=0.f, bF1=0.f;
        float aE2=0.f, aF2=0.f, bE2=0.f, bF2=0.f;

        for (int base = 0; base < nmax; base += 8) {
            int2 p1A[8], p1B[8], p2A[8], p2B[8];
            #pragma unroll
            for (int j = 0; j < 8; ++j) {
                int k = base + j;
                p1A[j] = ppA[(k < d1A) ? (s1A + k) : 0];
                p1B[j] = ppB[(k < d1B) ? (s1B + k) : 0];
                p2A[j] = ppA[(k < d2A) ? (s2A + k) : 0];
                p2B[j] = ppB[(k < d2B) ? (s2B + k) : 0];
            }
            float e1A[8], f1A[8], e1B[8], f1B[8];
            float e2A[8], f2A[8], e2B[8], f2B[8];
            #pragma unroll
            for (int j = 0; j < 8; ++j) {
                unsigned o1A = ((unsigned)p1A[j].x << 6) + (unsigned)lane;
                unsigned o1B = ((unsigned)p1B[j].x << 6) + (unsigned)lane;
                unsigned o2A = ((unsigned)p2A[j].x << 6) + (unsigned)lane;
                unsigned o2B = ((unsigned)p2B[j].x << 6) + (unsigned)lane;
                e1A[j] = e[o1A]; f1A[j] = f[o1A];
                e1B[j] = e[o1B]; f1B[j] = f[o1B];
                e2A[j] = e[o2A]; f2A[j] = f[o2A];
                e2B[j] = e[o2B]; f2B[j] = f[o2B];
            }
            #pragma unroll
            for (int j = 0; j < 8; ++j) {
                int k = base + j;
                float v1A = (k < d1A) ? __int_as_float(p1A[j].y) : 0.f;
                float v1B = (k < d1B) ? __int_as_float(p1B[j].y) : 0.f;
                float v2A = (k < d2A) ? __int_as_float(p2A[j].y) : 0.f;
                float v2B = (k < d2B) ? __int_as_float(p2B[j].y) : 0.f;
                aE1 = fmaf(v1A, e1A[j], aE1); aF1 = fmaf(v1A, f1A[j], aF1);
                bE1 = fmaf(v1B, e1B[j], bE1); bF1 = fmaf(v1B, f1B[j], bF1);
                aE2 = fmaf(v2A, e2A[j], aE2); aF2 = fmaf(v2A, f2A[j], aF2);
                bE2 = fmaf(v2B, e2B[j], bE2); bF2 = fmaf(v2B, f2B[j], bF2);
            }
        }

        if (set == 0) {
            float e3v, nev, f3v, nfv;
            node_math1(ev1, fv1, gd1, bd1, pd1, qd1, aE1, aF1, bE1, bF1,
                       e3v, nev, f3v, nfv);
            arrs[0*NF + idx1] = pack_bf(e3v);
            arrs[1*NF + idx1] = pack_bf(nev);
            arrs[4*NF + idx1] = pack_bf(f3v);
            arrs[5*NF + idx1] = pack_bf(nfv);
            pa0 += e3v*wa; pa1 += nev*wa; pa2 += f3v*wf; pa3 += nfv*wf;
            if (has2) {
                node_math1(ev2, fv2, gd2, bd2, pd2, qd2, aE2, aF2, bE2, bF2,
                           e3v, nev, f3v, nfv);
                arrs[0*NF + idx2] = pack_bf(e3v);
                arrs[1*NF + idx2] = pack_bf(nev);
                arrs[4*NF + idx2] = pack_bf(f3v);
                arrs[5*NF + idx2] = pack_bf(nfv);
                pa0 += e3v*wa; pa1 += nev*wa; pa2 += f3v*wf; pa3 += nfv*wf;
            }
        } else {
            arrs[2*NF + idx1] = pack_bf(aE1);   // e1
            arrs[3*NF + idx1] = pack_bf(bE1);   // e2
            arrs[6*NF + idx1] = pack_bf(aF1);   // f1
            arrs[7*NF + idx1] = pack_bf(bF1);   // f2
            pa0 += aE1*wa; pa1 += bE1*wa; pa2 += aF1*wf; pa3 += bF1*wf;
            if (has2) {
                arrs[2*NF + idx2] = pack_bf(aE2);
                arrs[3*NF + idx2] = pack_bf(bE2);
                arrs[6*NF + idx2] = pack_bf(aF2);
                arrs[7*NF + idx2] = pack_bf(bF2);
                pa0 += aE2*wa; pa1 += bE2*wa; pa2 += aF2*wf; pa3 += bF2*wf;
            }
        }
    }

    __shared__ float sred[4];
    if (tid < 4) sred[tid] = 0.f;
    __syncthreads();
    #pragma unroll
    for (int off = 32; off > 0; off >>= 1) {
        pa0 += __shfl_down(pa0, off); pa1 += __shfl_down(pa1, off);
        pa2 += __shfl_down(pa2, off); pa3 += __shfl_down(pa3, off);
    }
    if (lane == 0) {
        atomicAdd(&sred[0], pa0); atomicAdd(&sred[1], pa1);
        atomicAdd(&sred[2], pa2); atomicAdd(&sred[3], pa3);
    }
    __syncthreads();
    if (tid == 0) {
        float* pt = partials + ((size_t)g*NTILE + tile)*8;
        if (set == 0) { pt[0] = sred[0]; pt[1] = sred[1]; pt[4] = sred[2]; pt[5] = sred[3]; }
        else          { pt[2] = sred[0]; pt[3] = sred[1]; pt[6] = sred[2]; pt[7] = sred[3]; }
    }
}

// ---------------------------------------------------------------------------
// Kernel 4: MFMA epilogue with integrated attention finalize.
// Stages packed-bf16 uints into LDS in fragment order (10 segs), computes
// per-graph attention from partials, 5 per-segment accumulators, att folded
// post-MFMA, tanh + store.
// ---------------------------------------------------------------------------
__global__ __launch_bounds__(256) void final_fused(
    const float* __restrict__ e, const float* __restrict__ f,
    const unsigned* __restrict__ arrs, const float* __restrict__ partials,
    const float* __restrict__ b_ae, const float* __restrict__ b_af,
    const unsigned short* __restrict__ Wb1h, const unsigned short* __restrict__ Wb1l,
    const unsigned short* __restrict__ Wb2h, const unsigned short* __restrict__ Wb2l,
    const float* __restrict__ bv1, const float* __restrict__ bv2,
    float* __restrict__ out)
{
    __shared__ __align__(16) unsigned sfrag[80*132];
    __shared__ float satt[2][8];

    int tid = threadIdx.x, lane = tid & 63, chunk = tid >> 6;
    int node0 = blockIdx.x * 16;
    int sl = lane >> 3, jj = lane & 7;
    int g0 = node0 / N_NODES;
    int g1 = (node0 + 15) / N_NODES;

    // attention weights for the (<=2) graphs this block touches
    if (tid < 16) {
        int gi = tid >> 3, j = tid & 7;
        int gg = gi ? g1 : g0;
        float t = 0.f;
        for (int q = 0; q < NTILE; ++q)
            t += partials[((size_t)gg*NTILE + q)*8 + j];
        float bias = (j < 4) ? b_ae[0] : b_af[0];
        float x = t*(1.0f/N_NODES) + bias;
        satt[gi][j] = 1.0f/(1.0f + expf(-x));
    }

    #pragma unroll
    for (int round = 0; round < 4; ++round) {
        int ni = round*4 + chunk;
        size_t idx = (size_t)(node0 + ni)*FDIM + lane;
        #pragma unroll
        for (int seg = 0; seg < 10; ++seg) {
            unsigned u;
            if (seg == 4)      u = pack_bf(e[idx]);
            else if (seg == 9) u = pack_bf(f[idx]);
            else {
                int a = (seg < 4) ? seg : seg - 1;
                u = arrs[(size_t)a*NF + idx];
            }
            sfrag[(seg*8 + sl)*132 + ni*8 + jj] = u;
        }
    }
    __syncthreads();

    int m16 = lane & 15, quad = lane >> 4;
    float4v acce[5], accf[5];
    #pragma unroll
    for (int s = 0; s < 5; ++s) {
        acce[s] = (float4v){0.f,0.f,0.f,0.f};
        accf[s] = (float4v){0.f,0.f,0.f,0.f};
    }

    #pragma unroll
    for (int seg = 0; seg < 5; ++seg) {
        #pragma unroll
        for (int ks2 = 0; ks2 < 2; ++ks2) {
            int ks = seg*2 + ks2;
            size_t boff = (size_t)((ks*4 + chunk)*64 + lane)*8;
            {
                const unsigned* pa = &sfrag[(seg*8 + ks2*4 + quad)*132 + m16*8];
                uint4 ua = *(const uint4*)pa;
                uint4 ub = *(const uint4*)(pa + 4);
                unsigned uu[8] = {ua.x,ua.y,ua.z,ua.w,ub.x,ub.y,ub.z,ub.w};
                short8 ah, al;
                #pragma unroll
                for (int j = 0; j < 8; ++j) {
                    ah[j] = (short)(uu[j] >> 16);
                    al[j] = (short)(uu[j] & 0xFFFFu);
                }
                short8 bh = *(const short8*)(Wb1h + boff);
                short8 bl = *(const short8*)(Wb1l + boff);
                acce[seg] = __builtin_amdgcn_mfma_f32_16x16x32_bf16(ah, bh, acce[seg], 0, 0, 0);
                acce[seg] = __builtin_amdgcn_mfma_f32_16x16x32_bf16(al, bh, acce[seg], 0, 0, 0);
                acce[seg] = __builtin_amdgcn_mfma_f32_16x16x32_bf16(ah, bl, acce[seg], 0, 0, 0);
            }
            {
                const unsigned* pa = &sfrag[((seg+5)*8 + ks2*4 + quad)*132 + m16*8];
                uint4 ua = *(const uint4*)pa;
                uint4 ub = *(const uint4*)(pa + 4);
                unsigned uu[8] = {ua.x,ua.y,ua.z,ua.w,ub.x,ub.y,ub.z,ub.w};
                short8 ch, cl;
                #pragma unroll
                for (int j = 0; j < 8; ++j) {
                    ch[j] = (short)(uu[j] >> 16);
                    cl[j] = (short)(uu[j] & 0xFFFFu);
                }
                short8 bh = *(const short8*)(Wb2h + boff);
                short8 bl = *(const short8*)(Wb2l + boff);
                accf[seg] = __builtin_amdgcn_mfma_f32_16x16x32_bf16(ch, bh, accf[seg], 0, 0, 0);
                accf[seg] = __builtin_amdgcn_mfma_f32_16x16x32_bf16(cl, bh, accf[seg], 0, 0, 0);
                accf[seg] = __builtin_amdgcn_mfma_f32_16x16x32_bf16(ch, bl, accf[seg], 0, 0, 0);
            }
        }
    }

    int o = chunk*16 + m16;
    float be = bv1[o], bf = bv2[o];
    #pragma unroll
    for (int reg = 0; reg < 4; ++reg) {
        int node = node0 + quad*4 + reg;
        int gi = (node >= (g0+1)*N_NODES) ? 1 : 0;
        float den_e = 1e-4f + satt[gi][0] + satt[gi][1] + satt[gi][2] + satt[gi][3];
        float den_f = 1e-4f + satt[gi][4] + satt[gi][5] + satt[gi][6] + satt[gi][7];
        float inv_e = 1.0f/den_e, inv_f = 1.0f/den_f;
        float se2 = acce[4][reg];
        float sf2 = accf[4][reg];
        #pragma unroll
        for (int b = 0; b < 4; ++b) {
            se2 = fmaf(satt[gi][b]*inv_e,   acce[b][reg], se2);
            sf2 = fmaf(satt[gi][4+b]*inv_f, accf[b][reg], sf2);
        }
        out[(size_t)node*FDIM + o]      = tanhf(se2 + be);
        out[NF + (size_t)node*FDIM + o] = tanhf(sf2 + bf);
    }
}

// ---------------------------------------------------------------------------
extern "C" void kernel_launch(void* const* d_in, const int* in_sizes, int n_in,
                              void* d_out, int out_size, void* d_ws, size_t ws_size,
                              hipStream_t stream) {
    (void)in_sizes; (void)n_in; (void)out_size; (void)ws_size;
    const float* e     = (const float*)d_in[0];
    const float* f     = (const float*)d_in[1];
    const int*   rowsG = (const int*)d_in[2];
    const int*   colsG = (const int*)d_in[3];
    const float* valsG = (const float*)d_in[4];
    const int*   rowsB = (const int*)d_in[5];
    const int*   colsB = (const int*)d_in[6];
    const float* valsB = (const float*)d_in[7];
    const int*   rows1 = (const int*)d_in[8];
    const int*   cols1 = (const int*)d_in[9];
    const float* vals1 = (const float*)d_in[10];
    const int*   rows2 = (const int*)d_in[11];
    const int*   cols2 = (const int*)d_in[12];
    const float* vals2 = (const float*)d_in[13];
    const float* G_d   = (const float*)d_in[14];
    const float* B_d   = (const float*)d_in[15];
    const float* Pd    = (const float*)d_in[16];
    const float* Qd    = (const float*)d_in[17];
    const float* W1    = (const float*)d_in[18];
    const float* b1    = (const float*)d_in[19];
    const float* W2    = (const float*)d_in[20];
    const float* b2    = (const float*)d_in[21];
    const float* w_ae  = (const float*)d_in[22];
    const float* b_ae  = (const float*)d_in[23];
    const float* w_af  = (const float*)d_in[24];
    const float* b_af  = (const float*)d_in[25];

    unsigned* arrs  = (unsigned*)d_ws;               // 8*NF uints (packed bf16 h|l)
    float* partials = (float*)(arrs + 8*NF);         // 128*22*8 = 22528
    float* att_unused = partials + 22528;            // (reserved)
    unsigned short* Wb1h = (unsigned short*)(att_unused + 1024);  // 20480 each
    unsigned short* Wb1l = Wb1h + 20480;
    unsigned short* Wb2h = Wb1l + 20480;
    unsigned short* Wb2l = Wb2h + 20480;
    int*   offs     = (int*)(Wb2l + 20480);          // 512*OSTR ints
    int2*  pairs    = (int2*)(offs + 512*OSTR);      // 512*EPG int2

    csr_build<<<dim3(592), dim3(256), 0, stream>>>(
        rowsG, colsG, valsG, rowsB, colsB, valsB,
        rows1, cols1, vals1, rows2, cols2, vals2,
        W1, W2, Wb1h, Wb1l, Wb2h, Wb2l, offs, pairs);

    gather_all<<<dim3(5632), dim3(256), 0, stream>>>(
        e, f, G_d, B_d, Pd, Qd, w_ae, w_af, offs, pairs, arrs, partials);

    final_fused<<<dim3(NTOT/16), dim3(256), 0, stream>>>(
        e, f, arrs, partials, b_ae, b_af,
        Wb1h, Wb1l, Wb2h, Wb2l, b1, b2, (float*)d_out);
}